// Round 1
// baseline (1063.419 us; speedup 1.0000x reference)
//
#include <hip/hip_runtime.h>
#include <stdint.h>

#define BATCH 128
#define NTOK 4096
#define DD 64
#define NS 11
#define H3 192
#define MH 128
#define NCH 8

static __device__ __forceinline__ float bf2f(unsigned short u){
  union { unsigned int i; float f; } v; v.i = ((unsigned int)u) << 16; return v.f;
}
static __device__ __forceinline__ unsigned short f2bf(float f){
  union { float f; unsigned int i; } v; v.f = f;
  unsigned int r = v.i + 0x7fffu + ((v.i >> 16) & 1u);
  return (unsigned short)(r >> 16);
}
static __device__ __forceinline__ float lo16(unsigned int u){ union{unsigned int i;float f;}v; v.i = u << 16; return v.f; }
static __device__ __forceinline__ float hi16(unsigned int u){ union{unsigned int i;float f;}v; v.i = u & 0xffff0000u; return v.f; }

// ---------------------------------------------------------------------------
// Pass 1: x = LN(inputs); k = x@Wk; v = x@Wv  (k,v stored bf16)
// One thread per row (lane-per-row); weights transposed in LDS, broadcast reads.
// ---------------------------------------------------------------------------
__global__ __launch_bounds__(256) void proj_kernel(
    const float* __restrict__ in, const float* __restrict__ gin, const float* __restrict__ bin,
    const float* __restrict__ Wk, const float* __restrict__ Wv,
    unsigned short* __restrict__ kout, unsigned short* __restrict__ vout)
{
  __shared__ float WkT[64][64];
  __shared__ float WvT[64][64];
  for (int i = threadIdx.x; i < 4096; i += 256){
    int d = i >> 6, j = i & 63;
    WkT[j][d] = Wk[i];
    WvT[j][d] = Wv[i];
  }
  __syncthreads();
  long row = (long)blockIdx.x * 256 + threadIdx.x;
  const float* xr = in + row * 64;
  float x[64];
  #pragma unroll
  for (int i = 0; i < 16; i++){
    float4 t = ((const float4*)xr)[i];
    x[4*i+0]=t.x; x[4*i+1]=t.y; x[4*i+2]=t.z; x[4*i+3]=t.w;
  }
  float s = 0.f, s2 = 0.f;
  #pragma unroll
  for (int d = 0; d < 64; d++){ s += x[d]; s2 += x[d]*x[d]; }
  float m = s * (1.0f/64.0f);
  float var = s2 * (1.0f/64.0f) - m*m;
  float rs = rsqrtf(var + 1e-3f);
  #pragma unroll
  for (int d = 0; d < 64; d++){ x[d] = (x[d]-m)*rs*gin[d] + bin[d]; }
  unsigned short* krow = kout + row*64;
  unsigned short* vrow = vout + row*64;
  for (int jg = 0; jg < 8; jg++){
    float ak[8], av[8];
    #pragma unroll
    for (int u=0;u<8;u++){ ak[u]=0.f; av[u]=0.f; }
    #pragma unroll
    for (int d4 = 0; d4 < 16; d4++){
      #pragma unroll
      for (int u = 0; u < 8; u++){
        float4 wk = *(const float4*)&WkT[jg*8+u][d4*4];
        float4 wv = *(const float4*)&WvT[jg*8+u][d4*4];
        ak[u] += x[4*d4+0]*wk.x + x[4*d4+1]*wk.y + x[4*d4+2]*wk.z + x[4*d4+3]*wk.w;
        av[u] += x[4*d4+0]*wv.x + x[4*d4+1]*wv.y + x[4*d4+2]*wv.z + x[4*d4+3]*wv.w;
      }
    }
    uint4 kp, vp;
    kp.x = (unsigned)f2bf(ak[0]) | ((unsigned)f2bf(ak[1])<<16);
    kp.y = (unsigned)f2bf(ak[2]) | ((unsigned)f2bf(ak[3])<<16);
    kp.z = (unsigned)f2bf(ak[4]) | ((unsigned)f2bf(ak[5])<<16);
    kp.w = (unsigned)f2bf(ak[6]) | ((unsigned)f2bf(ak[7])<<16);
    vp.x = (unsigned)f2bf(av[0]) | ((unsigned)f2bf(av[1])<<16);
    vp.y = (unsigned)f2bf(av[2]) | ((unsigned)f2bf(av[3])<<16);
    vp.z = (unsigned)f2bf(av[4]) | ((unsigned)f2bf(av[5])<<16);
    vp.w = (unsigned)f2bf(av[6]) | ((unsigned)f2bf(av[7])<<16);
    *(uint4*)(krow + jg*8) = kp;
    *(uint4*)(vrow + jg*8) = vp;
  }
}

// ---------------------------------------------------------------------------
// Init: slots0 = mu + exp(log_sigma)*noise; q1 = LN(slots0)@Wq * scale
// ---------------------------------------------------------------------------
__global__ __launch_bounds__(256) void init_kernel(
    const float* __restrict__ noise, const float* __restrict__ mu, const float* __restrict__ ls,
    const float* __restrict__ g_slots, const float* __restrict__ b_slots, const float* __restrict__ Wq,
    float* __restrict__ slots_out, float* __restrict__ q_out)
{
  __shared__ float s0[NS][64], lnb[NS][64];
  __shared__ float stm[NS], str[NS];
  int b = blockIdx.x, t = threadIdx.x;
  for (int i=t;i<NS*64;i+=256){
    int d = i & 63;
    float v0 = mu[d] + __expf(ls[d]) * noise[b*NS*64 + i];
    s0[i>>6][d] = v0;
    slots_out[b*NS*64 + i] = v0;
  }
  __syncthreads();
  if (t < NS){
    float ssum=0.f, ssq=0.f;
    for (int d=0;d<64;d++){ float x0=s0[t][d]; ssum+=x0; ssq+=x0*x0; }
    float mm = ssum*(1.f/64.f);
    stm[t]=mm; str[t]=rsqrtf(ssq*(1.f/64.f) - mm*mm + 1e-3f);
  }
  __syncthreads();
  for (int i=t;i<NS*64;i+=256){ int s=i>>6,d=i&63; lnb[s][d] = (s0[s][d]-stm[s])*str[s]*g_slots[d] + b_slots[d]; }
  __syncthreads();
  for (int i=t;i<NS*64;i+=256){
    int s=i>>6, j=i&63;
    float a1=0.f;
    for (int d=0;d<64;d++) a1 += lnb[s][d]*Wq[d*64+j];
    q_out[b*NS*64+i] = a1*0.125f;
  }
}

// ---------------------------------------------------------------------------
// Attention pass: per (batch, chunk of 512 rows): logits -> softmax(+eps) ->
// per-chunk partial numerators (sum attn*v) and colsums (sum attn).
// Phase A lane-per-row, phase B dim-per-lane; deterministic reduction.
// ---------------------------------------------------------------------------
__global__ __launch_bounds__(256) void attn_kernel(
    const unsigned short* __restrict__ kk, const unsigned short* __restrict__ vv,
    const float* __restrict__ q, float* __restrict__ pnum, float* __restrict__ pcol)
{
  __shared__ float qs[NS][64];
  __shared__ float attnb[4][64][12];
  __shared__ float numl[4][NS][64];
  __shared__ float csl[4][NS];
  int b = blockIdx.x >> 3;
  int c = blockIdx.x & 7;
  int w = threadIdx.x >> 6;
  int lane = threadIdx.x & 63;
  for (int t = threadIdx.x; t < NS*64; t += 256) qs[t>>6][t&63] = q[b*(NS*64) + t];
  __syncthreads();
  float nump[NS], csp[NS];
  #pragma unroll
  for (int s=0;s<NS;s++){ nump[s]=0.f; csp[s]=0.f; }
  int rowbase = c*512 + w*128;
  for (int half = 0; half < 2; half++){
    int r0 = rowbase + half*64;
    {
      long row = (long)b*NTOK + r0 + lane;
      const uint4* kr = (const uint4*)(kk + row*64);
      float kx[64];
      #pragma unroll
      for (int i=0;i<8;i++){
        uint4 tt = kr[i];
        kx[8*i+0]=lo16(tt.x); kx[8*i+1]=hi16(tt.x);
        kx[8*i+2]=lo16(tt.y); kx[8*i+3]=hi16(tt.y);
        kx[8*i+4]=lo16(tt.z); kx[8*i+5]=hi16(tt.z);
        kx[8*i+6]=lo16(tt.w); kx[8*i+7]=hi16(tt.w);
      }
      float lg[NS];
      #pragma unroll
      for (int s=0;s<NS;s++) lg[s]=0.f;
      #pragma unroll
      for (int d4=0; d4<16; d4++){
        #pragma unroll
        for (int s=0;s<NS;s++){
          float4 qv = *(const float4*)&qs[s][d4*4];
          lg[s] += kx[4*d4+0]*qv.x + kx[4*d4+1]*qv.y + kx[4*d4+2]*qv.z + kx[4*d4+3]*qv.w;
        }
      }
      float mx = lg[0];
      #pragma unroll
      for (int s=1;s<NS;s++) mx = fmaxf(mx, lg[s]);
      float e[NS]; float sum = 0.f;
      #pragma unroll
      for (int s=0;s<NS;s++){ e[s] = __expf(lg[s]-mx); sum += e[s]; }
      float inv = 1.0f / sum;
      float a[12];
      #pragma unroll
      for (int s=0;s<NS;s++){ a[s] = e[s]*inv + 1e-8f; csp[s] += a[s]; }
      a[11] = 0.f;
      *(float4*)&attnb[w][lane][0] = make_float4(a[0],a[1],a[2],a[3]);
      *(float4*)&attnb[w][lane][4] = make_float4(a[4],a[5],a[6],a[7]);
      *(float4*)&attnb[w][lane][8] = make_float4(a[8],a[9],a[10],a[11]);
    }
    {
      const unsigned short* vb = vv + ((long)b*NTOK + r0)*64 + lane;
      #pragma unroll 4
      for (int r = 0; r < 64; r++){
        float vvx = bf2f(vb[r*64]);
        float4 a0 = *(const float4*)&attnb[w][r][0];
        float4 a1 = *(const float4*)&attnb[w][r][4];
        float4 a2 = *(const float4*)&attnb[w][r][8];
        nump[0] += a0.x*vvx; nump[1] += a0.y*vvx; nump[2] += a0.z*vvx; nump[3] += a0.w*vvx;
        nump[4] += a1.x*vvx; nump[5] += a1.y*vvx; nump[6] += a1.z*vvx; nump[7] += a1.w*vvx;
        nump[8] += a2.x*vvx; nump[9] += a2.y*vvx; nump[10] += a2.z*vvx;
      }
    }
  }
  #pragma unroll
  for (int s=0;s<NS;s++){
    float v0 = csp[s];
    for (int off=32; off>=1; off>>=1) v0 += __shfl_xor(v0, off);
    csp[s] = v0;
  }
  if (lane == 0){
    #pragma unroll
    for (int s=0;s<NS;s++) csl[w][s] = csp[s];
  }
  #pragma unroll
  for (int s=0;s<NS;s++) numl[w][s][lane] = nump[s];
  __syncthreads();
  int pbase = (b*NCH + c)*NS;
  for (int t = threadIdx.x; t < NS*64; t += 256){
    int s = t >> 6, d = t & 63;
    pnum[(pbase + s)*64 + d] = numl[0][s][d] + numl[1][s][d] + numl[2][s][d] + numl[3][s][d];
  }
  if (threadIdx.x < NS){
    pcol[pbase + threadIdx.x] = csl[0][threadIdx.x] + csl[1][threadIdx.x] + csl[2][threadIdx.x] + csl[3][threadIdx.x];
  }
}

// ---------------------------------------------------------------------------
// Per-batch slot update: reduce partials -> updates; GRU; LN+MLP residual;
// compute q for next iteration. One block per batch.
// ---------------------------------------------------------------------------
__global__ __launch_bounds__(512) void update_kernel(
    const float* __restrict__ pnum, const float* __restrict__ pcol,
    const float* __restrict__ slots_in,
    const float* __restrict__ K, const float* __restrict__ R, const float* __restrict__ bias,
    const float* __restrict__ W1, const float* __restrict__ b1,
    const float* __restrict__ W2, const float* __restrict__ b2,
    const float* __restrict__ g_slots, const float* __restrict__ b_slots,
    const float* __restrict__ g_mlp, const float* __restrict__ b_mlp,
    const float* __restrict__ Wq,
    float* __restrict__ slots_out, float* __restrict__ q_out,
    float* __restrict__ final_out, int last)
{
  __shared__ float upd[NS][64], sp[NS][64], sn[NS][64], lnb[NS][64], outb[NS][64];
  __shared__ float mx[NS][H3], mh[NS][H3];
  __shared__ float h1[NS][MH];
  __shared__ float cs[NS];
  __shared__ float stm[NS], str[NS];
  int b = blockIdx.x; int t = threadIdx.x; const int TB = 512;
  if (t < NS){
    float ssum = 0.f;
    for (int c2=0;c2<NCH;c2++) ssum += pcol[(b*NCH+c2)*NS + t];
    cs[t] = ssum;
  }
  __syncthreads();
  for (int i=t;i<NS*64;i+=TB){
    int s=i>>6, d=i&63;
    float acc=0.f;
    for (int c2=0;c2<NCH;c2++) acc += pnum[((b*NCH+c2)*NS+s)*64+d];
    upd[s][d] = acc / cs[s];
    sp[s][d] = slots_in[b*NS*64 + i];
  }
  __syncthreads();
  for (int i=t;i<NS*H3;i+=TB){
    int s=i/H3, j=i%H3;
    float a1 = bias[j], a2 = bias[H3+j];
    for (int d=0;d<64;d++){ a1 += upd[s][d]*K[d*H3+j]; a2 += sp[s][d]*R[d*H3+j]; }
    mx[s][j]=a1; mh[s][j]=a2;
  }
  __syncthreads();
  for (int i=t;i<NS*64;i+=TB){
    int s=i>>6, d=i&63;
    float z = 1.f/(1.f+__expf(-(mx[s][d]+mh[s][d])));
    float r = 1.f/(1.f+__expf(-(mx[s][64+d]+mh[s][64+d])));
    float cand = tanhf(mx[s][128+d] + r*mh[s][128+d]);
    sn[s][d] = z*sp[s][d] + (1.f-z)*cand;
  }
  __syncthreads();
  if (t < NS){
    float ssum=0.f, ssq=0.f;
    for (int d=0;d<64;d++){ float x0=sn[t][d]; ssum+=x0; ssq+=x0*x0; }
    float mm = ssum*(1.f/64.f);
    stm[t]=mm; str[t]=rsqrtf(ssq*(1.f/64.f) - mm*mm + 1e-3f);
  }
  __syncthreads();
  for (int i=t;i<NS*64;i+=TB){ int s=i>>6,d=i&63; lnb[s][d] = (sn[s][d]-stm[s])*str[s]*g_mlp[d] + b_mlp[d]; }
  __syncthreads();
  for (int i=t;i<NS*MH;i+=TB){
    int s=i/MH, j=i%MH;
    float a1 = b1[j];
    for (int d=0;d<64;d++) a1 += lnb[s][d]*W1[d*MH+j];
    h1[s][j] = fmaxf(a1, 0.f);
  }
  __syncthreads();
  for (int i=t;i<NS*64;i+=TB){
    int s=i>>6, d=i&63;
    float a1 = sn[s][d] + b2[d];
    for (int j=0;j<MH;j++) a1 += h1[s][j]*W2[j*64+d];
    outb[s][d]=a1;
    slots_out[b*NS*64+i] = a1;
    if (last) final_out[b*NS*64+i] = a1;
  }
  __syncthreads();
  if (t < NS){
    float ssum=0.f, ssq=0.f;
    for (int d=0;d<64;d++){ float x0=outb[t][d]; ssum+=x0; ssq+=x0*x0; }
    float mm = ssum*(1.f/64.f);
    stm[t]=mm; str[t]=rsqrtf(ssq*(1.f/64.f) - mm*mm + 1e-3f);
  }
  __syncthreads();
  for (int i=t;i<NS*64;i+=TB){ int s=i>>6,d=i&63; lnb[s][d] = (outb[s][d]-stm[s])*str[s]*g_slots[d] + b_slots[d]; }
  __syncthreads();
  for (int i=t;i<NS*64;i+=TB){
    int s=i>>6, j=i&63;
    float a1=0.f;
    for (int d=0;d<64;d++) a1 += lnb[s][d]*Wq[d*64+j];
    q_out[b*NS*64+i] = a1*0.125f;
  }
}

extern "C" void kernel_launch(void* const* d_in, const int* in_sizes, int n_in,
                              void* d_out, int out_size, void* d_ws, size_t ws_size,
                              hipStream_t stream)
{
  const float* inputs = (const float*)d_in[0];
  const float* noise  = (const float*)d_in[1];
  const float* gin    = (const float*)d_in[2];
  const float* bin    = (const float*)d_in[3];
  const float* gsl    = (const float*)d_in[4];
  const float* bsl    = (const float*)d_in[5];
  const float* gml    = (const float*)d_in[6];
  const float* bml    = (const float*)d_in[7];
  const float* mu     = (const float*)d_in[8];
  const float* lsg    = (const float*)d_in[9];
  const float* Wq     = (const float*)d_in[10];
  const float* Wk     = (const float*)d_in[11];
  const float* Wv     = (const float*)d_in[12];
  const float* gk     = (const float*)d_in[13];
  const float* gr     = (const float*)d_in[14];
  const float* gb     = (const float*)d_in[15];
  const float* W1     = (const float*)d_in[16];
  const float* b1     = (const float*)d_in[17];
  const float* W2     = (const float*)d_in[18];
  const float* b2     = (const float*)d_in[19];

  char* ws = (char*)d_ws;
  unsigned short* kbuf = (unsigned short*)(ws);
  unsigned short* vbuf = (unsigned short*)(ws + 67108864);
  float* qbuf  = (float*)(ws + 134217728);
  float* slots = (float*)(ws + 134217728 + 524288);
  float* pnum  = (float*)(ws + 134217728 + 1048576);
  float* pcol  = (float*)(ws + 134217728 + 1048576 + 2883584);
  float* out   = (float*)d_out;

  hipLaunchKernelGGL(proj_kernel, dim3(2048), dim3(256), 0, stream, inputs, gin, bin, Wk, Wv, kbuf, vbuf);
  hipLaunchKernelGGL(init_kernel, dim3(128), dim3(256), 0, stream, noise, mu, lsg, gsl, bsl, Wq, slots, qbuf);
  for (int it = 0; it < 3; it++){
    hipLaunchKernelGGL(attn_kernel, dim3(1024), dim3(256), 0, stream, kbuf, vbuf, qbuf, pnum, pcol);
    hipLaunchKernelGGL(update_kernel, dim3(128), dim3(512), 0, stream,
        pnum, pcol, slots, gk, gr, gb, W1, b1, W2, b2, gsl, bsl, gml, bml, Wq,
        slots, qbuf, out, (it==2) ? 1 : 0);
  }
}

// Round 2
// 735.568 us; speedup vs baseline: 1.4457x; 1.4457x over previous
//
#include <hip/hip_runtime.h>
#include <stdint.h>

#define BATCH 128
#define NTOK 4096
#define DD 64
#define NS 11
#define H3 192
#define MH 128
#define NCH 8
#define AST 72  // LDS A-tile row stride in bf16 elements (64 data + 8 pad)

typedef __attribute__((ext_vector_type(8))) short bf16x8;
typedef __attribute__((ext_vector_type(4))) float f32x4;

static __device__ __forceinline__ float bf2f(unsigned short u){
  union { unsigned int i; float f; } v; v.i = ((unsigned int)u) << 16; return v.f;
}
static __device__ __forceinline__ unsigned short f2bf(float f){
  union { float f; unsigned int i; } v; v.f = f;
  unsigned int r = v.i + 0x7fffu + ((v.i >> 16) & 1u);
  return (unsigned short)(r >> 16);
}
static __device__ __forceinline__ unsigned int pack2(float a, float b){
  return (unsigned int)f2bf(a) | ((unsigned int)f2bf(b) << 16);
}
static __device__ __forceinline__ float lo16(unsigned int u){ union{unsigned int i;float f;}v; v.i = u << 16; return v.f; }
static __device__ __forceinline__ float hi16(unsigned int u){ union{unsigned int i;float f;}v; v.i = u & 0xffff0000u; return v.f; }

// ---------------------------------------------------------------------------
// prep_w: fold LN gamma into [Wk|Wv] (bf16, packed per-lane for MFMA B-frags),
// and beta into a fp32 bias row.  Runs once, 1 block.
// Pack layout: wpack[(((ks*8+ct)*64)+l)*8 + e] = g[k]*W[k][j],
//   k = ks*32 + (l>>4)*8 + e,  j = ct*16 + (l&15)   (j<64 -> Wk, else Wv)
// ---------------------------------------------------------------------------
__global__ __launch_bounds__(256) void prep_w(
    const float* __restrict__ gin, const float* __restrict__ bin,
    const float* __restrict__ Wk, const float* __restrict__ Wv,
    unsigned short* __restrict__ wpack, float* __restrict__ wbias)
{
  __shared__ float W2[64][128];
  int t = threadIdx.x;
  for (int i = t; i < 64*128; i += 256){
    int d = i >> 7, j = i & 127;
    W2[d][j] = (j < 64) ? Wk[d*64 + j] : Wv[d*64 + (j-64)];
  }
  __syncthreads();
  for (int j = t; j < 128; j += 256){
    float s = 0.f;
    for (int d = 0; d < 64; d++) s += bin[d] * W2[d][j];
    wbias[j] = s;
  }
  for (int i = t; i < 8192; i += 256){
    int e = i & 7;
    int l = (i >> 3) & 63;
    int ctks = i >> 9;         // 0..15
    int ks = ctks >> 3, ct = ctks & 7;
    int k = ks*32 + ((l >> 4) * 8) + e;
    int j = ct*16 + (l & 15);
    wpack[i] = f2bf(gin[k] * W2[k][j]);
  }
}

// ---------------------------------------------------------------------------
// proj_mfma: x_hat = (x-m)*rsqrt(var+eps) per row (gamma/beta folded into W);
// [k|v] = x_hat @ Wpack + bias via mfma_f32_16x16x32_bf16.
// 256 threads = 4 waves; 256 rows per block; wave w owns rows w*64..w*64+63.
// ---------------------------------------------------------------------------
__global__ __launch_bounds__(256) void proj_mfma(
    const float* __restrict__ in,
    const unsigned short* __restrict__ wpack, const float* __restrict__ wbias,
    unsigned short* __restrict__ kout, unsigned short* __restrict__ vout)
{
  __shared__ unsigned short Asm[256*AST];   // 36864 B
  __shared__ unsigned short Wsm[8192];      // 16384 B
  __shared__ float Bias[128];
  int t = threadIdx.x;
  for (int i = t; i < 1024; i += 256) ((uint4*)Wsm)[i] = ((const uint4*)wpack)[i];
  if (t < 128) Bias[t] = wbias[t];

  // ---- LN: one row per thread ----
  long row = (long)blockIdx.x * 256 + t;
  const float4* xr = (const float4*)(in + row * 64);
  float x[64];
  #pragma unroll
  for (int i = 0; i < 16; i++){
    float4 v = xr[i];
    x[4*i+0]=v.x; x[4*i+1]=v.y; x[4*i+2]=v.z; x[4*i+3]=v.w;
  }
  float s = 0.f, s2 = 0.f;
  #pragma unroll
  for (int d = 0; d < 64; d++){ s += x[d]; s2 += x[d]*x[d]; }
  float m = s * (1.0f/64.0f);
  float var = s2 * (1.0f/64.0f) - m*m;
  float rs = rsqrtf(var + 1e-3f);
  unsigned short* ar = Asm + t * AST;
  #pragma unroll
  for (int i2 = 0; i2 < 8; i2++){
    uint4 p;
    p.x = pack2((x[8*i2+0]-m)*rs, (x[8*i2+1]-m)*rs);
    p.y = pack2((x[8*i2+2]-m)*rs, (x[8*i2+3]-m)*rs);
    p.z = pack2((x[8*i2+4]-m)*rs, (x[8*i2+5]-m)*rs);
    p.w = pack2((x[8*i2+6]-m)*rs, (x[8*i2+7]-m)*rs);
    *(uint4*)(ar + i2*8) = p;
  }
  __syncthreads();

  // ---- MFMA: wave w -> rows [w*64, w*64+64) ----
  int w = t >> 6, l = t & 63;
  int g = l >> 4, ln16 = l & 15;
  float biasr[8];
  #pragma unroll
  for (int ct = 0; ct < 8; ct++) biasr[ct] = Bias[ct*16 + ln16];

  for (int rt = 0; rt < 4; rt++){
    int rbase = w*64 + rt*16;
    const unsigned short* arow = Asm + (rbase + ln16) * AST;
    bf16x8 a0 = *(const bf16x8*)(arow + g*8);        // k = 0*32 + g*8 + e
    bf16x8 a1 = *(const bf16x8*)(arow + 32 + g*8);   // k = 1*32 + g*8 + e
    f32x4 acc[8];
    #pragma unroll
    for (int ct = 0; ct < 8; ct++){
      float bb = biasr[ct];
      acc[ct][0]=bb; acc[ct][1]=bb; acc[ct][2]=bb; acc[ct][3]=bb;
    }
    #pragma unroll
    for (int ct = 0; ct < 8; ct++){
      bf16x8 b0 = *(const bf16x8*)(Wsm + ((0*8 + ct)*64 + l)*8);
      bf16x8 b1 = *(const bf16x8*)(Wsm + ((1*8 + ct)*64 + l)*8);
      acc[ct] = __builtin_amdgcn_mfma_f32_16x16x32_bf16(a0, b0, acc[ct], 0, 0, 0);
      acc[ct] = __builtin_amdgcn_mfma_f32_16x16x32_bf16(a1, b1, acc[ct], 0, 0, 0);
    }
    // D: row(within tile) = g*4+e, col = ct*16 + ln16
    long ob = (long)blockIdx.x*256 + rbase + g*4;
    #pragma unroll
    for (int e = 0; e < 4; e++){
      unsigned short* kr = kout + (ob + e)*64 + ln16;
      unsigned short* vr = vout + (ob + e)*64 + ln16;
      kr[0]  = f2bf(acc[0][e]);
      kr[16] = f2bf(acc[1][e]);
      kr[32] = f2bf(acc[2][e]);
      kr[48] = f2bf(acc[3][e]);
      vr[0]  = f2bf(acc[4][e]);
      vr[16] = f2bf(acc[5][e]);
      vr[32] = f2bf(acc[6][e]);
      vr[48] = f2bf(acc[7][e]);
    }
  }
}

// ---------------------------------------------------------------------------
// Init: slots0 = mu + exp(log_sigma)*noise; q1 = LN(slots0)@Wq * scale
// ---------------------------------------------------------------------------
__global__ __launch_bounds__(256) void init_kernel(
    const float* __restrict__ noise, const float* __restrict__ mu, const float* __restrict__ ls,
    const float* __restrict__ g_slots, const float* __restrict__ b_slots, const float* __restrict__ Wq,
    float* __restrict__ slots_out, float* __restrict__ q_out)
{
  __shared__ float s0[NS][64], lnb[NS][64];
  __shared__ float stm[NS], str[NS];
  int b = blockIdx.x, t = threadIdx.x;
  for (int i=t;i<NS*64;i+=256){
    int d = i & 63;
    float v0 = mu[d] + __expf(ls[d]) * noise[b*NS*64 + i];
    s0[i>>6][d] = v0;
    slots_out[b*NS*64 + i] = v0;
  }
  __syncthreads();
  if (t < NS){
    float ssum=0.f, ssq=0.f;
    for (int d=0;d<64;d++){ float x0=s0[t][d]; ssum+=x0; ssq+=x0*x0; }
    float mm = ssum*(1.f/64.f);
    stm[t]=mm; str[t]=rsqrtf(ssq*(1.f/64.f) - mm*mm + 1e-3f);
  }
  __syncthreads();
  for (int i=t;i<NS*64;i+=256){ int s=i>>6,d=i&63; lnb[s][d] = (s0[s][d]-stm[s])*str[s]*g_slots[d] + b_slots[d]; }
  __syncthreads();
  for (int i=t;i<NS*64;i+=256){
    int s=i>>6, j=i&63;
    float a1=0.f;
    for (int d=0;d<64;d++) a1 += lnb[s][d]*Wq[d*64+j];
    q_out[b*NS*64+i] = a1*0.125f;
  }
}

// ---------------------------------------------------------------------------
// Attention pass: per (batch, chunk of 512 rows): logits -> softmax(+eps) ->
// per-chunk partial numerators (sum attn*v) and colsums (sum attn).
// ---------------------------------------------------------------------------
__global__ __launch_bounds__(256) void attn_kernel(
    const unsigned short* __restrict__ kk, const unsigned short* __restrict__ vv,
    const float* __restrict__ q, float* __restrict__ pnum, float* __restrict__ pcol)
{
  __shared__ float qs[NS][64];
  __shared__ float attnb[4][64][12];
  __shared__ float numl[4][NS][64];
  __shared__ float csl[4][NS];
  int b = blockIdx.x >> 3;
  int c = blockIdx.x & 7;
  int w = threadIdx.x >> 6;
  int lane = threadIdx.x & 63;
  for (int t = threadIdx.x; t < NS*64; t += 256) qs[t>>6][t&63] = q[b*(NS*64) + t];
  __syncthreads();
  float nump[NS], csp[NS];
  #pragma unroll
  for (int s=0;s<NS;s++){ nump[s]=0.f; csp[s]=0.f; }
  int rowbase = c*512 + w*128;
  for (int half = 0; half < 2; half++){
    int r0 = rowbase + half*64;
    {
      long row = (long)b*NTOK + r0 + lane;
      const uint4* kr = (const uint4*)(kk + row*64);
      float kx[64];
      #pragma unroll
      for (int i=0;i<8;i++){
        uint4 tt = kr[i];
        kx[8*i+0]=lo16(tt.x); kx[8*i+1]=hi16(tt.x);
        kx[8*i+2]=lo16(tt.y); kx[8*i+3]=hi16(tt.y);
        kx[8*i+4]=lo16(tt.z); kx[8*i+5]=hi16(tt.z);
        kx[8*i+6]=lo16(tt.w); kx[8*i+7]=hi16(tt.w);
      }
      float lg[NS];
      #pragma unroll
      for (int s=0;s<NS;s++) lg[s]=0.f;
      #pragma unroll
      for (int d4=0; d4<16; d4++){
        #pragma unroll
        for (int s=0;s<NS;s++){
          float4 qv = *(const float4*)&qs[s][d4*4];
          lg[s] += kx[4*d4+0]*qv.x + kx[4*d4+1]*qv.y + kx[4*d4+2]*qv.z + kx[4*d4+3]*qv.w;
        }
      }
      float mx = lg[0];
      #pragma unroll
      for (int s=1;s<NS;s++) mx = fmaxf(mx, lg[s]);
      float e[NS]; float sum = 0.f;
      #pragma unroll
      for (int s=0;s<NS;s++){ e[s] = __expf(lg[s]-mx); sum += e[s]; }
      float inv = 1.0f / sum;
      float a[12];
      #pragma unroll
      for (int s=0;s<NS;s++){ a[s] = e[s]*inv + 1e-8f; csp[s] += a[s]; }
      a[11] = 0.f;
      *(float4*)&attnb[w][lane][0] = make_float4(a[0],a[1],a[2],a[3]);
      *(float4*)&attnb[w][lane][4] = make_float4(a[4],a[5],a[6],a[7]);
      *(float4*)&attnb[w][lane][8] = make_float4(a[8],a[9],a[10],a[11]);
    }
    {
      const unsigned short* vb = vv + ((long)b*NTOK + r0)*64 + lane;
      #pragma unroll 4
      for (int r = 0; r < 64; r++){
        float vvx = bf2f(vb[r*64]);
        float4 a0 = *(const float4*)&attnb[w][r][0];
        float4 a1 = *(const float4*)&attnb[w][r][4];
        float4 a2 = *(const float4*)&attnb[w][r][8];
        nump[0] += a0.x*vvx; nump[1] += a0.y*vvx; nump[2] += a0.z*vvx; nump[3] += a0.w*vvx;
        nump[4] += a1.x*vvx; nump[5] += a1.y*vvx; nump[6] += a1.z*vvx; nump[7] += a1.w*vvx;
        nump[8] += a2.x*vvx; nump[9] += a2.y*vvx; nump[10] += a2.z*vvx;
      }
    }
  }
  #pragma unroll
  for (int s=0;s<NS;s++){
    float v0 = csp[s];
    for (int off=32; off>=1; off>>=1) v0 += __shfl_xor(v0, off);
    csp[s] = v0;
  }
  if (lane == 0){
    #pragma unroll
    for (int s=0;s<NS;s++) csl[w][s] = csp[s];
  }
  #pragma unroll
  for (int s=0;s<NS;s++) numl[w][s][lane] = nump[s];
  __syncthreads();
  int pbase = (b*NCH + c)*NS;
  for (int t = threadIdx.x; t < NS*64; t += 256){
    int s = t >> 6, d = t & 63;
    pnum[(pbase + s)*64 + d] = numl[0][s][d] + numl[1][s][d] + numl[2][s][d] + numl[3][s][d];
  }
  if (threadIdx.x < NS){
    pcol[pbase + threadIdx.x] = csl[0][threadIdx.x] + csl[1][threadIdx.x] + csl[2][threadIdx.x] + csl[3][threadIdx.x];
  }
}

// ---------------------------------------------------------------------------
// Per-batch slot update: reduce partials -> updates; GRU; LN+MLP residual;
// compute q for next iteration. One block per batch.
// ---------------------------------------------------------------------------
__global__ __launch_bounds__(512) void update_kernel(
    const float* __restrict__ pnum, const float* __restrict__ pcol,
    const float* __restrict__ slots_in,
    const float* __restrict__ K, const float* __restrict__ R, const float* __restrict__ bias,
    const float* __restrict__ W1, const float* __restrict__ b1,
    const float* __restrict__ W2, const float* __restrict__ b2,
    const float* __restrict__ g_slots, const float* __restrict__ b_slots,
    const float* __restrict__ g_mlp, const float* __restrict__ b_mlp,
    const float* __restrict__ Wq,
    float* __restrict__ slots_out, float* __restrict__ q_out,
    float* __restrict__ final_out, int last)
{
  __shared__ float upd[NS][64], sp[NS][64], sn[NS][64], lnb[NS][64], outb[NS][64];
  __shared__ float mx[NS][H3], mh[NS][H3];
  __shared__ float h1[NS][MH];
  __shared__ float cs[NS];
  __shared__ float stm[NS], str[NS];
  int b = blockIdx.x; int t = threadIdx.x; const int TB = 512;
  if (t < NS){
    float ssum = 0.f;
    for (int c2=0;c2<NCH;c2++) ssum += pcol[(b*NCH+c2)*NS + t];
    cs[t] = ssum;
  }
  __syncthreads();
  for (int i=t;i<NS*64;i+=TB){
    int s=i>>6, d=i&63;
    float acc=0.f;
    for (int c2=0;c2<NCH;c2++) acc += pnum[((b*NCH+c2)*NS+s)*64+d];
    upd[s][d] = acc / cs[s];
    sp[s][d] = slots_in[b*NS*64 + i];
  }
  __syncthreads();
  for (int i=t;i<NS*H3;i+=TB){
    int s=i/H3, j=i%H3;
    float a1 = bias[j], a2 = bias[H3+j];
    for (int d=0;d<64;d++){ a1 += upd[s][d]*K[d*H3+j]; a2 += sp[s][d]*R[d*H3+j]; }
    mx[s][j]=a1; mh[s][j]=a2;
  }
  __syncthreads();
  for (int i=t;i<NS*64;i+=TB){
    int s=i>>6, d=i&63;
    float z = 1.f/(1.f+__expf(-(mx[s][d]+mh[s][d])));
    float r = 1.f/(1.f+__expf(-(mx[s][64+d]+mh[s][64+d])));
    float cand = tanhf(mx[s][128+d] + r*mh[s][128+d]);
    sn[s][d] = z*sp[s][d] + (1.f-z)*cand;
  }
  __syncthreads();
  if (t < NS){
    float ssum=0.f, ssq=0.f;
    for (int d=0;d<64;d++){ float x0=sn[t][d]; ssum+=x0; ssq+=x0*x0; }
    float mm = ssum*(1.f/64.f);
    stm[t]=mm; str[t]=rsqrtf(ssq*(1.f/64.f) - mm*mm + 1e-3f);
  }
  __syncthreads();
  for (int i=t;i<NS*64;i+=TB){ int s=i>>6,d=i&63; lnb[s][d] = (sn[s][d]-stm[s])*str[s]*g_mlp[d] + b_mlp[d]; }
  __syncthreads();
  for (int i=t;i<NS*MH;i+=TB){
    int s=i/MH, j=i%MH;
    float a1 = b1[j];
    for (int d=0;d<64;d++) a1 += lnb[s][d]*W1[d*MH+j];
    h1[s][j] = fmaxf(a1, 0.f);
  }
  __syncthreads();
  for (int i=t;i<NS*64;i+=TB){
    int s=i>>6, d=i&63;
    float a1 = sn[s][d] + b2[d];
    for (int j=0;j<MH;j++) a1 += h1[s][j]*W2[j*64+d];
    outb[s][d]=a1;
    slots_out[b*NS*64+i] = a1;
    if (last) final_out[b*NS*64+i] = a1;
  }
  __syncthreads();
  if (t < NS){
    float ssum=0.f, ssq=0.f;
    for (int d=0;d<64;d++){ float x0=outb[t][d]; ssum+=x0; ssq+=x0*x0; }
    float mm = ssum*(1.f/64.f);
    stm[t]=mm; str[t]=rsqrtf(ssq*(1.f/64.f) - mm*mm + 1e-3f);
  }
  __syncthreads();
  for (int i=t;i<NS*64;i+=TB){ int s=i>>6,d=i&63; lnb[s][d] = (outb[s][d]-stm[s])*str[s]*g_slots[d] + b_slots[d]; }
  __syncthreads();
  for (int i=t;i<NS*64;i+=TB){
    int s=i>>6, j=i&63;
    float a1=0.f;
    for (int d=0;d<64;d++) a1 += lnb[s][d]*Wq[d*64+j];
    q_out[b*NS*64+i] = a1*0.125f;
  }
}

extern "C" void kernel_launch(void* const* d_in, const int* in_sizes, int n_in,
                              void* d_out, int out_size, void* d_ws, size_t ws_size,
                              hipStream_t stream)
{
  const float* inputs = (const float*)d_in[0];
  const float* noise  = (const float*)d_in[1];
  const float* gin    = (const float*)d_in[2];
  const float* bin    = (const float*)d_in[3];
  const float* gsl    = (const float*)d_in[4];
  const float* bsl    = (const float*)d_in[5];
  const float* gml    = (const float*)d_in[6];
  const float* bml    = (const float*)d_in[7];
  const float* mu     = (const float*)d_in[8];
  const float* lsg    = (const float*)d_in[9];
  const float* Wq     = (const float*)d_in[10];
  const float* Wk     = (const float*)d_in[11];
  const float* Wv     = (const float*)d_in[12];
  const float* gk     = (const float*)d_in[13];
  const float* gr     = (const float*)d_in[14];
  const float* gb     = (const float*)d_in[15];
  const float* W1     = (const float*)d_in[16];
  const float* b1     = (const float*)d_in[17];
  const float* W2     = (const float*)d_in[18];
  const float* b2     = (const float*)d_in[19];

  char* ws = (char*)d_ws;
  unsigned short* kbuf = (unsigned short*)(ws);
  unsigned short* vbuf = (unsigned short*)(ws + 67108864);
  float* qbuf  = (float*)(ws + 134217728);
  float* slots = (float*)(ws + 134217728 + 524288);
  float* pnum  = (float*)(ws + 134217728 + 1048576);
  float* pcol  = (float*)(ws + 134217728 + 1048576 + 2883584);
  unsigned short* wpack = (unsigned short*)(ws + 138194944);
  float* wbias = (float*)(ws + 138194944 + 16384);
  float* out   = (float*)d_out;

  hipLaunchKernelGGL(prep_w, dim3(1), dim3(256), 0, stream, gin, bin, Wk, Wv, wpack, wbias);
  hipLaunchKernelGGL(proj_mfma, dim3(2048), dim3(256), 0, stream, inputs, wpack, wbias, kbuf, vbuf);
  hipLaunchKernelGGL(init_kernel, dim3(128), dim3(256), 0, stream, noise, mu, lsg, gsl, bsl, Wq, slots, qbuf);
  for (int it = 0; it < 3; it++){
    hipLaunchKernelGGL(attn_kernel, dim3(1024), dim3(256), 0, stream, kbuf, vbuf, qbuf, pnum, pcol);
    hipLaunchKernelGGL(update_kernel, dim3(128), dim3(512), 0, stream,
        pnum, pcol, slots, gk, gr, gb, W1, b1, W2, b2, gsl, bsl, gml, bml, Wq,
        slots, qbuf, out, (it==2) ? 1 : 0);
  }
}

// Round 3
// 248.081 us; speedup vs baseline: 4.2866x; 2.9650x over previous
//
#include <hip/hip_runtime.h>
#include <stdint.h>

#define BATCH 128
#define NTOK 4096
#define DD 64
#define NS 11
#define H3 192
#define MH 128
#define NCH 8
#define AST 72  // LDS A-tile row stride in bf16 elements (64 data + 8 pad)

typedef __attribute__((ext_vector_type(8))) short bf16x8;
typedef __attribute__((ext_vector_type(4))) float f32x4;

static __device__ __forceinline__ float bf2f(unsigned short u){
  union { unsigned int i; float f; } v; v.i = ((unsigned int)u) << 16; return v.f;
}
static __device__ __forceinline__ unsigned short f2bf(float f){
  union { float f; unsigned int i; } v; v.f = f;
  unsigned int r = v.i + 0x7fffu + ((v.i >> 16) & 1u);
  return (unsigned short)(r >> 16);
}
static __device__ __forceinline__ unsigned int pack2(float a, float b){
  return (unsigned int)f2bf(a) | ((unsigned int)f2bf(b) << 16);
}
static __device__ __forceinline__ float lo16(unsigned int u){ union{unsigned int i;float f;}v; v.i = u << 16; return v.f; }
static __device__ __forceinline__ float hi16(unsigned int u){ union{unsigned int i;float f;}v; v.i = u & 0xffff0000u; return v.f; }

// ---------------------------------------------------------------------------
// prep_w: fold LN gamma into [Wk|Wv] (bf16, packed per-lane for MFMA B-frags),
// and beta into a fp32 bias row.  Runs once, 1 block.
// ---------------------------------------------------------------------------
__global__ __launch_bounds__(256) void prep_w(
    const float* __restrict__ gin, const float* __restrict__ bin,
    const float* __restrict__ Wk, const float* __restrict__ Wv,
    unsigned short* __restrict__ wpack, float* __restrict__ wbias)
{
  __shared__ float W2[64][128];
  int t = threadIdx.x;
  for (int i = t; i < 64*128; i += 256){
    int d = i >> 7, j = i & 127;
    W2[d][j] = (j < 64) ? Wk[d*64 + j] : Wv[d*64 + (j-64)];
  }
  __syncthreads();
  for (int j = t; j < 128; j += 256){
    float s = 0.f;
    for (int d = 0; d < 64; d++) s += bin[d] * W2[d][j];
    wbias[j] = s;
  }
  for (int i = t; i < 8192; i += 256){
    int e = i & 7;
    int l = (i >> 3) & 63;
    int ctks = i >> 9;         // 0..15
    int ks = ctks >> 3, ct = ctks & 7;
    int k = ks*32 + ((l >> 4) * 8) + e;
    int j = ct*16 + (l & 15);
    wpack[i] = f2bf(gin[k] * W2[k][j]);
  }
}

// ---------------------------------------------------------------------------
// proj_mfma: LN (gamma/beta folded into W) + [k|v] = x_hat @ Wpack + bias.
// ---------------------------------------------------------------------------
__global__ __launch_bounds__(256) void proj_mfma(
    const float* __restrict__ in,
    const unsigned short* __restrict__ wpack, const float* __restrict__ wbias,
    unsigned short* __restrict__ kout, unsigned short* __restrict__ vout)
{
  __shared__ unsigned short Asm[256*AST];   // 36864 B
  __shared__ unsigned short Wsm[8192];      // 16384 B
  __shared__ float Bias[128];
  int t = threadIdx.x;
  for (int i = t; i < 1024; i += 256) ((uint4*)Wsm)[i] = ((const uint4*)wpack)[i];
  if (t < 128) Bias[t] = wbias[t];

  long row = (long)blockIdx.x * 256 + t;
  const float4* xr = (const float4*)(in + row * 64);
  float x[64];
  #pragma unroll
  for (int i = 0; i < 16; i++){
    float4 v = xr[i];
    x[4*i+0]=v.x; x[4*i+1]=v.y; x[4*i+2]=v.z; x[4*i+3]=v.w;
  }
  float s = 0.f, s2 = 0.f;
  #pragma unroll
  for (int d = 0; d < 64; d++){ s += x[d]; s2 += x[d]*x[d]; }
  float m = s * (1.0f/64.0f);
  float var = s2 * (1.0f/64.0f) - m*m;
  float rs = rsqrtf(var + 1e-3f);
  unsigned short* ar = Asm + t * AST;
  #pragma unroll
  for (int i2 = 0; i2 < 8; i2++){
    uint4 p;
    p.x = pack2((x[8*i2+0]-m)*rs, (x[8*i2+1]-m)*rs);
    p.y = pack2((x[8*i2+2]-m)*rs, (x[8*i2+3]-m)*rs);
    p.z = pack2((x[8*i2+4]-m)*rs, (x[8*i2+5]-m)*rs);
    p.w = pack2((x[8*i2+6]-m)*rs, (x[8*i2+7]-m)*rs);
    *(uint4*)(ar + i2*8) = p;
  }
  __syncthreads();

  int w = t >> 6, l = t & 63;
  int g = l >> 4, ln16 = l & 15;
  float biasr[8];
  #pragma unroll
  for (int ct = 0; ct < 8; ct++) biasr[ct] = Bias[ct*16 + ln16];

  for (int rt = 0; rt < 4; rt++){
    int rbase = w*64 + rt*16;
    const unsigned short* arow = Asm + (rbase + ln16) * AST;
    bf16x8 a0 = *(const bf16x8*)(arow + g*8);
    bf16x8 a1 = *(const bf16x8*)(arow + 32 + g*8);
    f32x4 acc[8];
    #pragma unroll
    for (int ct = 0; ct < 8; ct++){
      float bb = biasr[ct];
      acc[ct][0]=bb; acc[ct][1]=bb; acc[ct][2]=bb; acc[ct][3]=bb;
    }
    #pragma unroll
    for (int ct = 0; ct < 8; ct++){
      bf16x8 b0 = *(const bf16x8*)(Wsm + ((0*8 + ct)*64 + l)*8);
      bf16x8 b1 = *(const bf16x8*)(Wsm + ((1*8 + ct)*64 + l)*8);
      acc[ct] = __builtin_amdgcn_mfma_f32_16x16x32_bf16(a0, b0, acc[ct], 0, 0, 0);
      acc[ct] = __builtin_amdgcn_mfma_f32_16x16x32_bf16(a1, b1, acc[ct], 0, 0, 0);
    }
    long ob = (long)blockIdx.x*256 + rbase + g*4;
    #pragma unroll
    for (int e = 0; e < 4; e++){
      unsigned short* kr = kout + (ob + e)*64 + ln16;
      unsigned short* vr = vout + (ob + e)*64 + ln16;
      kr[0]  = f2bf(acc[0][e]);
      kr[16] = f2bf(acc[1][e]);
      kr[32] = f2bf(acc[2][e]);
      kr[48] = f2bf(acc[3][e]);
      vr[0]  = f2bf(acc[4][e]);
      vr[16] = f2bf(acc[5][e]);
      vr[32] = f2bf(acc[6][e]);
      vr[48] = f2bf(acc[7][e]);
    }
  }
}

// ---------------------------------------------------------------------------
// Init: slots0 = mu + exp(log_sigma)*noise; q1 = LN(slots0)@Wq * scale
// ---------------------------------------------------------------------------
__global__ __launch_bounds__(256) void init_kernel(
    const float* __restrict__ noise, const float* __restrict__ mu, const float* __restrict__ ls,
    const float* __restrict__ g_slots, const float* __restrict__ b_slots, const float* __restrict__ Wq,
    float* __restrict__ slots_out, float* __restrict__ q_out)
{
  __shared__ float s0[NS][64], lnb[NS][64];
  __shared__ float stm[NS], str[NS];
  int b = blockIdx.x, t = threadIdx.x;
  for (int i=t;i<NS*64;i+=256){
    int d = i & 63;
    float v0 = mu[d] + __expf(ls[d]) * noise[b*NS*64 + i];
    s0[i>>6][d] = v0;
    slots_out[b*NS*64 + i] = v0;
  }
  __syncthreads();
  if (t < NS){
    float ssum=0.f, ssq=0.f;
    for (int d=0;d<64;d++){ float x0=s0[t][d]; ssum+=x0; ssq+=x0*x0; }
    float mm = ssum*(1.f/64.f);
    stm[t]=mm; str[t]=rsqrtf(ssq*(1.f/64.f) - mm*mm + 1e-3f);
  }
  __syncthreads();
  for (int i=t;i<NS*64;i+=256){ int s=i>>6,d=i&63; lnb[s][d] = (s0[s][d]-stm[s])*str[s]*g_slots[d] + b_slots[d]; }
  __syncthreads();
  for (int i=t;i<NS*64;i+=256){
    int s=i>>6, j=i&63;
    float a1=0.f;
    for (int d=0;d<64;d++) a1 += lnb[s][d]*Wq[d*64+j];
    q_out[b*NS*64+i] = a1*0.125f;
  }
}

// ---------------------------------------------------------------------------
// Attention pass (MFMA QK^T, swapped operands + vectorized PV):
// grid = (batch, chunk of 512 rows); block = 4 waves, 128 rows/wave.
// Phase A: per 16 rows: B-frag = k rows (wide loads), A-frag = q^T;
//   D[m=slot][n=row]; softmax over slots via 2x shfl_xor; attn -> LDS.
// Phase B: lane=(rowgrp,dimgrp): 8B v loads, 44 FMAs/step; shfl reduce.
// ---------------------------------------------------------------------------
__global__ __launch_bounds__(256) void attn_kernel(
    const unsigned short* __restrict__ kk, const unsigned short* __restrict__ vv,
    const float* __restrict__ q, float* __restrict__ pnum, float* __restrict__ pcol)
{
  __shared__ float qsp[16][64];
  __shared__ float attnb[4][128][12];
  __shared__ float numl[4][NS][64];
  __shared__ float csl[4][16];
  int b = blockIdx.x >> 3;
  int c = blockIdx.x & 7;
  int w = threadIdx.x >> 6;
  int l = threadIdx.x & 63;
  int t = threadIdx.x;
  for (int i = t; i < 16*64; i += 256){
    int s = i >> 6, d = i & 63;
    qsp[s][d] = (s < NS) ? q[b*(NS*64) + i] : 0.f;
  }
  __syncthreads();
  int ln16 = l & 15, g = l >> 4;
  // A-frags: A[m=slot=ln16][k=dim=g*8+e] (+32 for second K-slice)
  bf16x8 aq0, aq1;
  #pragma unroll
  for (int e = 0; e < 8; e++){
    aq0[e] = (short)f2bf(qsp[ln16][g*8 + e]);
    aq1[e] = (short)f2bf(qsp[ln16][32 + g*8 + e]);
  }
  bool v0 = (g*4+0) < NS, v1 = (g*4+1) < NS, v2 = (g*4+2) < NS, v3 = (g*4+3) < NS;
  float csp0=0.f, csp1=0.f, csp2=0.f, csp3=0.f;
  long rowbase = (long)b*NTOK + c*512 + w*128;
  #pragma unroll 2
  for (int grp = 0; grp < 8; grp++){
    long row = rowbase + grp*16 + ln16;
    const unsigned short* kp = kk + row*64 + g*8;
    bf16x8 kb0 = *(const bf16x8*)(kp);
    bf16x8 kb1 = *(const bf16x8*)(kp + 32);
    f32x4 acc = {0.f,0.f,0.f,0.f};
    acc = __builtin_amdgcn_mfma_f32_16x16x32_bf16(aq0, kb0, acc, 0, 0, 0);
    acc = __builtin_amdgcn_mfma_f32_16x16x32_bf16(aq1, kb1, acc, 0, 0, 0);
    // lane holds logits[slot = g*4+r][row = grp*16+ln16]
    float mx = fmaxf(fmaxf(v0?acc[0]:-1e30f, v1?acc[1]:-1e30f),
                     fmaxf(v2?acc[2]:-1e30f, v3?acc[3]:-1e30f));
    mx = fmaxf(mx, __shfl_xor(mx, 16));
    mx = fmaxf(mx, __shfl_xor(mx, 32));
    float e0 = v0 ? __expf(acc[0]-mx) : 0.f;
    float e1 = v1 ? __expf(acc[1]-mx) : 0.f;
    float e2 = v2 ? __expf(acc[2]-mx) : 0.f;
    float e3 = v3 ? __expf(acc[3]-mx) : 0.f;
    float ssum = (e0+e1)+(e2+e3);
    ssum += __shfl_xor(ssum, 16);
    ssum += __shfl_xor(ssum, 32);
    float inv = 1.f/ssum;
    float a0 = v0 ? e0*inv + 1e-8f : 0.f;
    float a1 = v1 ? e1*inv + 1e-8f : 0.f;
    float a2 = v2 ? e2*inv + 1e-8f : 0.f;
    float a3 = v3 ? e3*inv + 1e-8f : 0.f;
    csp0 += a0; csp1 += a1; csp2 += a2; csp3 += a3;
    if (g < 3){
      *(float4*)&attnb[w][grp*16+ln16][g*4] = make_float4(a0,a1,a2,a3);
    }
  }
  // colsum: sum across rows (= across ln16 lanes)
  #pragma unroll
  for (int off = 1; off <= 8; off <<= 1){
    csp0 += __shfl_xor(csp0, off);
    csp1 += __shfl_xor(csp1, off);
    csp2 += __shfl_xor(csp2, off);
    csp3 += __shfl_xor(csp3, off);
  }
  if (ln16 == 0){
    csl[w][g*4+0] = csp0;
    csl[w][g*4+1] = csp1;
    csl[w][g*4+2] = csp2;
    csl[w][g*4+3] = csp3;
  }
  __syncthreads();

  // ---- Phase B: PV ----
  int dg = ln16;   // dims dg*4 .. +4
  int rg = g;      // row-group: rows step*4 + rg
  float nump[NS][4];
  #pragma unroll
  for (int s2=0;s2<NS;s2++){
    #pragma unroll
    for (int j=0;j<4;j++) nump[s2][j]=0.f;
  }
  const unsigned short* vbase = vv + rowbase*64;
  #pragma unroll 4
  for (int step = 0; step < 32; step++){
    int row = step*4 + rg;
    uint2 vp = *(const uint2*)(vbase + row*64 + dg*4);
    float vf0 = lo16(vp.x), vf1 = hi16(vp.x), vf2 = lo16(vp.y), vf3 = hi16(vp.y);
    float4 a0 = *(const float4*)&attnb[w][row][0];
    float4 a1 = *(const float4*)&attnb[w][row][4];
    float4 a2 = *(const float4*)&attnb[w][row][8];
    float av[NS] = {a0.x,a0.y,a0.z,a0.w, a1.x,a1.y,a1.z,a1.w, a2.x,a2.y,a2.z};
    #pragma unroll
    for (int s2 = 0; s2 < NS; s2++){
      nump[s2][0] += av[s2]*vf0;
      nump[s2][1] += av[s2]*vf1;
      nump[s2][2] += av[s2]*vf2;
      nump[s2][3] += av[s2]*vf3;
    }
  }
  #pragma unroll
  for (int s2 = 0; s2 < NS; s2++){
    #pragma unroll
    for (int j = 0; j < 4; j++){
      nump[s2][j] += __shfl_xor(nump[s2][j], 16);
      nump[s2][j] += __shfl_xor(nump[s2][j], 32);
    }
  }
  if (rg == 0){
    #pragma unroll
    for (int s2 = 0; s2 < NS; s2++){
      *(float4*)&numl[w][s2][dg*4] = make_float4(nump[s2][0], nump[s2][1], nump[s2][2], nump[s2][3]);
    }
  }
  __syncthreads();
  int pbase = (b*NCH + c)*NS;
  for (int i = t; i < NS*64; i += 256){
    int s2 = i >> 6, d = i & 63;
    pnum[(pbase + s2)*64 + d] = numl[0][s2][d] + numl[1][s2][d] + numl[2][s2][d] + numl[3][s2][d];
  }
  if (t < NS){
    pcol[pbase + t] = csl[0][t] + csl[1][t] + csl[2][t] + csl[3][t];
  }
}

// ---------------------------------------------------------------------------
// Per-batch slot update: reduce partials -> updates; GRU; LN+MLP residual;
// compute q for next iteration. One block per batch.
// ---------------------------------------------------------------------------
__global__ __launch_bounds__(512) void update_kernel(
    const float* __restrict__ pnum, const float* __restrict__ pcol,
    const float* __restrict__ slots_in,
    const float* __restrict__ K, const float* __restrict__ R, const float* __restrict__ bias,
    const float* __restrict__ W1, const float* __restrict__ b1,
    const float* __restrict__ W2, const float* __restrict__ b2,
    const float* __restrict__ g_slots, const float* __restrict__ b_slots,
    const float* __restrict__ g_mlp, const float* __restrict__ b_mlp,
    const float* __restrict__ Wq,
    float* __restrict__ slots_out, float* __restrict__ q_out,
    float* __restrict__ final_out, int last)
{
  __shared__ float upd[NS][64], sp[NS][64], sn[NS][64], lnb[NS][64], outb[NS][64];
  __shared__ float mx[NS][H3], mh[NS][H3];
  __shared__ float h1[NS][MH];
  __shared__ float cs[NS];
  __shared__ float stm[NS], str[NS];
  int b = blockIdx.x; int t = threadIdx.x; const int TB = 512;
  if (t < NS){
    float ssum = 0.f;
    for (int c2=0;c2<NCH;c2++) ssum += pcol[(b*NCH+c2)*NS + t];
    cs[t] = ssum;
  }
  __syncthreads();
  for (int i=t;i<NS*64;i+=TB){
    int s=i>>6, d=i&63;
    float acc=0.f;
    for (int c2=0;c2<NCH;c2++) acc += pnum[((b*NCH+c2)*NS+s)*64+d];
    upd[s][d] = acc / cs[s];
    sp[s][d] = slots_in[b*NS*64 + i];
  }
  __syncthreads();
  for (int i=t;i<NS*H3;i+=TB){
    int s=i/H3, j=i%H3;
    float a1 = bias[j], a2 = bias[H3+j];
    for (int d=0;d<64;d++){ a1 += upd[s][d]*K[d*H3+j]; a2 += sp[s][d]*R[d*H3+j]; }
    mx[s][j]=a1; mh[s][j]=a2;
  }
  __syncthreads();
  for (int i=t;i<NS*64;i+=TB){
    int s=i>>6, d=i&63;
    float z = 1.f/(1.f+__expf(-(mx[s][d]+mh[s][d])));
    float r = 1.f/(1.f+__expf(-(mx[s][64+d]+mh[s][64+d])));
    float cand = tanhf(mx[s][128+d] + r*mh[s][128+d]);
    sn[s][d] = z*sp[s][d] + (1.f-z)*cand;
  }
  __syncthreads();
  if (t < NS){
    float ssum=0.f, ssq=0.f;
    for (int d=0;d<64;d++){ float x0=sn[t][d]; ssum+=x0; ssq+=x0*x0; }
    float mm = ssum*(1.f/64.f);
    stm[t]=mm; str[t]=rsqrtf(ssq*(1.f/64.f) - mm*mm + 1e-3f);
  }
  __syncthreads();
  for (int i=t;i<NS*64;i+=TB){ int s=i>>6,d=i&63; lnb[s][d] = (sn[s][d]-stm[s])*str[s]*g_mlp[d] + b_mlp[d]; }
  __syncthreads();
  for (int i=t;i<NS*MH;i+=TB){
    int s=i/MH, j=i%MH;
    float a1 = b1[j];
    for (int d=0;d<64;d++) a1 += lnb[s][d]*W1[d*MH+j];
    h1[s][j] = fmaxf(a1, 0.f);
  }
  __syncthreads();
  for (int i=t;i<NS*64;i+=TB){
    int s=i>>6, d=i&63;
    float a1 = sn[s][d] + b2[d];
    for (int j=0;j<MH;j++) a1 += h1[s][j]*W2[j*64+d];
    outb[s][d]=a1;
    slots_out[b*NS*64+i] = a1;
    if (last) final_out[b*NS*64+i] = a1;
  }
  __syncthreads();
  if (t < NS){
    float ssum=0.f, ssq=0.f;
    for (int d=0;d<64;d++){ float x0=outb[t][d]; ssum+=x0; ssq+=x0*x0; }
    float mm = ssum*(1.f/64.f);
    stm[t]=mm; str[t]=rsqrtf(ssq*(1.f/64.f) - mm*mm + 1e-3f);
  }
  __syncthreads();
  for (int i=t;i<NS*64;i+=TB){ int s=i>>6,d=i&63; lnb[s][d] = (outb[s][d]-stm[s])*str[s]*g_slots[d] + b_slots[d]; }
  __syncthreads();
  for (int i=t;i<NS*64;i+=TB){
    int s=i>>6, j=i&63;
    float a1=0.f;
    for (int d=0;d<64;d++) a1 += lnb[s][d]*Wq[d*64+j];
    q_out[b*NS*64+i] = a1*0.125f;
  }
}

extern "C" void kernel_launch(void* const* d_in, const int* in_sizes, int n_in,
                              void* d_out, int out_size, void* d_ws, size_t ws_size,
                              hipStream_t stream)
{
  const float* inputs = (const float*)d_in[0];
  const float* noise  = (const float*)d_in[1];
  const float* gin    = (const float*)d_in[2];
  const float* bin    = (const float*)d_in[3];
  const float* gsl    = (const float*)d_in[4];
  const float* bsl    = (const float*)d_in[5];
  const float* gml    = (const float*)d_in[6];
  const float* bml    = (const float*)d_in[7];
  const float* mu     = (const float*)d_in[8];
  const float* lsg    = (const float*)d_in[9];
  const float* Wq     = (const float*)d_in[10];
  const float* Wk     = (const float*)d_in[11];
  const float* Wv     = (const float*)d_in[12];
  const float* gk     = (const float*)d_in[13];
  const float* gr     = (const float*)d_in[14];
  const float* gb     = (const float*)d_in[15];
  const float* W1     = (const float*)d_in[16];
  const float* b1     = (const float*)d_in[17];
  const float* W2     = (const float*)d_in[18];
  const float* b2     = (const float*)d_in[19];

  char* ws = (char*)d_ws;
  unsigned short* kbuf = (unsigned short*)(ws);
  unsigned short* vbuf = (unsigned short*)(ws + 67108864);
  float* qbuf  = (float*)(ws + 134217728);
  float* slots = (float*)(ws + 134217728 + 524288);
  float* pnum  = (float*)(ws + 134217728 + 1048576);
  float* pcol  = (float*)(ws + 134217728 + 1048576 + 2883584);
  unsigned short* wpack = (unsigned short*)(ws + 138194944);
  float* wbias = (float*)(ws + 138194944 + 16384);
  float* out   = (float*)d_out;

  hipLaunchKernelGGL(prep_w, dim3(1), dim3(256), 0, stream, gin, bin, Wk, Wv, wpack, wbias);
  hipLaunchKernelGGL(proj_mfma, dim3(2048), dim3(256), 0, stream, inputs, wpack, wbias, kbuf, vbuf);
  hipLaunchKernelGGL(init_kernel, dim3(128), dim3(256), 0, stream, noise, mu, lsg, gsl, bsl, Wq, slots, qbuf);
  for (int it = 0; it < 3; it++){
    hipLaunchKernelGGL(attn_kernel, dim3(1024), dim3(256), 0, stream, kbuf, vbuf, qbuf, pnum, pcol);
    hipLaunchKernelGGL(update_kernel, dim3(128), dim3(512), 0, stream,
        pnum, pcol, slots, gk, gr, gb, W1, b1, W2, b2, gsl, bsl, gml, bml, Wq,
        slots, qbuf, out, (it==2) ? 1 : 0);
  }
}